// Round 3
// baseline (258.419 us; speedup 1.0000x reference)
//
#include <hip/hip_runtime.h>
#include <math.h>

#define L 512
#define NCH 21      // channels in x
#define H 30        // seq_hmm rows
#define NAA 20      // aa channels used (x[:,1:,:])
#define WSTRIDE 50  // W is [3, 20+H] = [3, 50]

typedef float v4f __attribute__((ext_vector_type(4)));

// Fully fused: one block per sample b; 128 threads; thread t owns columns
// 4t..4t+3. Each thread recomputes its own slice of the seq_hmm projection
// (L2-resident, ~1 µs total extra VALU) -- no separate kernel, no d_ws.
// NOTE: precise expf/logf required -- __expf/__logf fail absmax (R2: 2.7e-2).
__global__ __launch_bounds__(128) void qpml_fused(
        const float* __restrict__ x,        // [B,21,L]
        const float* __restrict__ seq_hmm,  // [H,L]
        const float* __restrict__ ss_hmm,   // [3,L]
        const float* __restrict__ W,        // [3,50]
        const float* __restrict__ bvec,     // [3]
        float* __restrict__ out) {          // [B]
    const int b = blockIdx.x;
    const int t = threadIdx.x;  // 0..127
    const float* xb = x + (size_t)b * NCH * L;

    // stage all of W (150 floats) + b (3 floats) into LDS
    __shared__ float sW[3][WSTRIDE];
    __shared__ float sb[3];
    if (t < 3 * WSTRIDE) ((float*)sW)[t] = W[t];
    if (t < 3) sb[t] = bvec[t];
    __syncthreads();

    const int l0 = 4 * t;

    // accumulators init to bias
    float a[3][4];
#pragma unroll
    for (int o = 0; o < 3; ++o) {
        const float bo = sb[o];
#pragma unroll
        for (int j = 0; j < 4; ++j) a[o][j] = bo;
    }

    // proj contribution from the shared profile (L2-resident after first use)
#pragma unroll
    for (int h = 0; h < H; ++h) {
        const v4f s = *(const v4f*)(seq_hmm + h * L + l0);
        const float w0 = sW[0][NAA + h];
        const float w1 = sW[1][NAA + h];
        const float w2 = sW[2][NAA + h];
#pragma unroll
        for (int j = 0; j < 4; ++j) {
            a[0][j] = fmaf(w0, s[j], a[0][j]);
            a[1][j] = fmaf(w1, s[j], a[1][j]);
            a[2][j] = fmaf(w2, s[j], a[2][j]);
        }
    }

    // gap channel (c=0): nontemporal streaming read
    float xg[4], m[4];
    {
        const v4f v = __builtin_nontemporal_load((const v4f*)(xb + l0));
#pragma unroll
        for (int j = 0; j < 4; ++j) { xg[j] = v[j]; m[j] = -INFINITY; }
    }

    // aa channels 1..20: fused max + weighted accumulate
#pragma unroll
    for (int c = 1; c < NCH; ++c) {
        const v4f v = __builtin_nontemporal_load((const v4f*)(xb + c * L + l0));
        const float w0 = sW[0][c - 1];
        const float w1 = sW[1][c - 1];
        const float w2 = sW[2][c - 1];
#pragma unroll
        for (int j = 0; j < 4; ++j) {
            m[j] = fmaxf(m[j], v[j]);
            a[0][j] = fmaf(w0, v[j], a[0][j]);
            a[1][j] = fmaf(w1, v[j], a[1][j]);
            a[2][j] = fmaf(w2, v[j], a[2][j]);
        }
    }

    // ss weights for these columns (tiny, cached)
    float wss[3][4];
#pragma unroll
    for (int o = 0; o < 3; ++o) {
        const v4f s = *(const v4f*)(ss_hmm + o * L + l0);
#pragma unroll
        for (int j = 0; j < 4; ++j) wss[o][j] = s[j];
    }

    float lsum = 0.0f, lcnt = 0.0f;
#pragma unroll
    for (int j = 0; j < 4; ++j) {
        if (m[j] > xg[j]) {  // argmax != 0 (first-occurrence tie -> gap)
            const float mm = fmaxf(a[0][j], fmaxf(a[1][j], a[2][j]));
            const float e0 = expf(a[0][j] - mm);
            const float e1 = expf(a[1][j] - mm);
            const float e2 = expf(a[2][j] - mm);
            const float inv = 1.0f / (e0 + e1 + e2);
            lsum = fmaf(wss[0][j] * e0 + wss[1][j] * e1 + wss[2][j] * e2, inv, lsum);
            lcnt += 1.0f;
        }
    }

    // 64-lane wave shuffle reduction
#pragma unroll
    for (int off = 32; off >= 1; off >>= 1) {
        lsum += __shfl_down(lsum, off);
        lcnt += __shfl_down(lcnt, off);
    }

    __shared__ float s_s[2], s_c[2];
    if ((t & 63) == 0) { s_s[t >> 6] = lsum; s_c[t >> 6] = lcnt; }
    __syncthreads();
    if (t == 0) {
        out[b] = logf((s_s[0] + s_s[1]) / (s_c[0] + s_c[1]));
    }
}

extern "C" void kernel_launch(void* const* d_in, const int* in_sizes, int n_in,
                              void* d_out, int out_size, void* d_ws, size_t ws_size,
                              hipStream_t stream) {
    const float* x       = (const float*)d_in[0];  // [4096,21,512]
    const float* seq_hmm = (const float*)d_in[1];  // [30,512]
    const float* ss_hmm  = (const float*)d_in[2];  // [3,512]
    const float* W       = (const float*)d_in[3];  // [3,50]
    const float* bvec    = (const float*)d_in[4];  // [3]
    float* out = (float*)d_out;                    // [4096]

    const int B = in_sizes[0] / (NCH * L);  // 4096
    qpml_fused<<<B, 128, 0, stream>>>(x, seq_hmm, ss_hmm, W, bvec, out);
}

// Round 4
// 254.440 us; speedup vs baseline: 1.0156x; 1.0156x over previous
//
#include <hip/hip_runtime.h>
#include <math.h>

#define L 512
#define NCH 21      // channels in x
#define H 30        // seq_hmm rows
#define NAA 20      // aa channels used (x[:,1:,:])
#define WSTRIDE 50  // W is [3, 20+H] = [3, 50]

typedef float v4f __attribute__((ext_vector_type(4)));

// Fully fused: one block per sample b; 128 threads; thread t owns columns
// 4t..4t+3. Each thread recomputes its own slice of the seq_hmm projection
// (L2/L3-resident) -- no separate kernel, no d_ws.
// NOTE: precise expf/logf required -- __expf/__logf fail absmax (R2: 2.7e-2).
// NOTE: plain cached loads for x -- nontemporal bypassed L3 and cost ~10 µs
//       (R3: harness's pre-replay restore leaves x hot in Infinity Cache).
__global__ __launch_bounds__(128) void qpml_fused(
        const float* __restrict__ x,        // [B,21,L]
        const float* __restrict__ seq_hmm,  // [H,L]
        const float* __restrict__ ss_hmm,   // [3,L]
        const float* __restrict__ W,        // [3,50]
        const float* __restrict__ bvec,     // [3]
        float* __restrict__ out) {          // [B]
    const int b = blockIdx.x;
    const int t = threadIdx.x;  // 0..127
    const float* xb = x + (size_t)b * NCH * L;

    // stage all of W (150 floats) + b (3 floats) into LDS
    __shared__ float sW[3][WSTRIDE];
    __shared__ float sb[3];
    if (t < 3 * WSTRIDE) ((float*)sW)[t] = W[t];
    if (t < 3) sb[t] = bvec[t];
    __syncthreads();

    const int l0 = 4 * t;

    // accumulators init to bias
    float a[3][4];
#pragma unroll
    for (int o = 0; o < 3; ++o) {
        const float bo = sb[o];
#pragma unroll
        for (int j = 0; j < 4; ++j) a[o][j] = bo;
    }

    // proj contribution from the shared profile (L2-resident after first use)
#pragma unroll
    for (int h = 0; h < H; ++h) {
        const v4f s = *(const v4f*)(seq_hmm + h * L + l0);
        const float w0 = sW[0][NAA + h];
        const float w1 = sW[1][NAA + h];
        const float w2 = sW[2][NAA + h];
#pragma unroll
        for (int j = 0; j < 4; ++j) {
            a[0][j] = fmaf(w0, s[j], a[0][j]);
            a[1][j] = fmaf(w1, s[j], a[1][j]);
            a[2][j] = fmaf(w2, s[j], a[2][j]);
        }
    }

    // gap channel (c=0)
    float xg[4], m[4];
    {
        const v4f v = *(const v4f*)(xb + l0);
#pragma unroll
        for (int j = 0; j < 4; ++j) { xg[j] = v[j]; m[j] = -INFINITY; }
    }

    // aa channels 1..20: fused max + weighted accumulate
#pragma unroll
    for (int c = 1; c < NCH; ++c) {
        const v4f v = *(const v4f*)(xb + c * L + l0);
        const float w0 = sW[0][c - 1];
        const float w1 = sW[1][c - 1];
        const float w2 = sW[2][c - 1];
#pragma unroll
        for (int j = 0; j < 4; ++j) {
            m[j] = fmaxf(m[j], v[j]);
            a[0][j] = fmaf(w0, v[j], a[0][j]);
            a[1][j] = fmaf(w1, v[j], a[1][j]);
            a[2][j] = fmaf(w2, v[j], a[2][j]);
        }
    }

    // ss weights for these columns (tiny, cached)
    float wss[3][4];
#pragma unroll
    for (int o = 0; o < 3; ++o) {
        const v4f s = *(const v4f*)(ss_hmm + o * L + l0);
#pragma unroll
        for (int j = 0; j < 4; ++j) wss[o][j] = s[j];
    }

    float lsum = 0.0f, lcnt = 0.0f;
#pragma unroll
    for (int j = 0; j < 4; ++j) {
        if (m[j] > xg[j]) {  // argmax != 0 (first-occurrence tie -> gap)
            const float mm = fmaxf(a[0][j], fmaxf(a[1][j], a[2][j]));
            const float e0 = expf(a[0][j] - mm);
            const float e1 = expf(a[1][j] - mm);
            const float e2 = expf(a[2][j] - mm);
            const float inv = 1.0f / (e0 + e1 + e2);
            lsum = fmaf(wss[0][j] * e0 + wss[1][j] * e1 + wss[2][j] * e2, inv, lsum);
            lcnt += 1.0f;
        }
    }

    // 64-lane wave shuffle reduction
#pragma unroll
    for (int off = 32; off >= 1; off >>= 1) {
        lsum += __shfl_down(lsum, off);
        lcnt += __shfl_down(lcnt, off);
    }

    __shared__ float s_s[2], s_c[2];
    if ((t & 63) == 0) { s_s[t >> 6] = lsum; s_c[t >> 6] = lcnt; }
    __syncthreads();
    if (t == 0) {
        out[b] = logf((s_s[0] + s_s[1]) / (s_c[0] + s_c[1]));
    }
}

extern "C" void kernel_launch(void* const* d_in, const int* in_sizes, int n_in,
                              void* d_out, int out_size, void* d_ws, size_t ws_size,
                              hipStream_t stream) {
    const float* x       = (const float*)d_in[0];  // [4096,21,512]
    const float* seq_hmm = (const float*)d_in[1];  // [30,512]
    const float* ss_hmm  = (const float*)d_in[2];  // [3,512]
    const float* W       = (const float*)d_in[3];  // [3,50]
    const float* bvec    = (const float*)d_in[4];  // [3]
    float* out = (float*)d_out;                    // [4096]

    const int B = in_sizes[0] / (NCH * L);  // 4096
    qpml_fused<<<B, 128, 0, stream>>>(x, seq_hmm, ss_hmm, W, bvec, out);
}

// Round 5
// 245.425 us; speedup vs baseline: 1.0529x; 1.0367x over previous
//
#include <hip/hip_runtime.h>
#include <math.h>

#define L 512
#define NCH 21      // channels in x
#define H 30        // seq_hmm rows
#define NAA 20      // aa channels used (x[:,1:,:])
#define WSTRIDE 50  // W is [3, 20+H] = [3, 50]

typedef float v4f __attribute__((ext_vector_type(4)));

// proj[o*L + l] = sum_h W[o][20+h] * seq_hmm[h][l] + b[o]
// One-time precompute (R1-proven: cheaper than per-block recompute, R4 -6us).
__global__ void precompute_proj(const float* __restrict__ seq_hmm,
                                const float* __restrict__ W,
                                const float* __restrict__ bvec,
                                float* __restrict__ proj) {
    const int l = threadIdx.x;  // 512 threads, 1 block
    float a0 = bvec[0], a1 = bvec[1], a2 = bvec[2];
#pragma unroll
    for (int h = 0; h < H; ++h) {
        const float s = seq_hmm[h * L + l];
        a0 = fmaf(W[0 * WSTRIDE + NAA + h], s, a0);
        a1 = fmaf(W[1 * WSTRIDE + NAA + h], s, a1);
        a2 = fmaf(W[2 * WSTRIDE + NAA + h], s, a2);
    }
    proj[0 * L + l] = a0;
    proj[1 * L + l] = a1;
    proj[2 * L + l] = a2;
}

// One block per sample b; 128 threads; thread t owns columns 4t..4t+3.
// NOTE: precise expf/logf required -- __expf/__logf fail absmax (R2: 2.7e-2).
// NOTE: plain cached loads -- nontemporal bypassed L3, +4-10us (R3/R4).
__global__ __launch_bounds__(128) void qpml_main(
        const float* __restrict__ x,       // [B,21,L]
        const float* __restrict__ ss_hmm,  // [3,L]
        const float* __restrict__ W,       // [3,50]
        const float* __restrict__ proj,    // [3,L]
        float* __restrict__ out) {         // [B]
    const int b = blockIdx.x;
    const int t = threadIdx.x;  // 0..127
    const float* xb = x + (size_t)b * NCH * L;

    // stage W[o][0..19] into LDS
    __shared__ float sW[3][NAA];
    if (t < 3 * NAA) ((float*)sW)[t] = W[(t / NAA) * WSTRIDE + (t % NAA)];
    __syncthreads();

    const int l0 = 4 * t;

    // channel 0 (gap channel) values
    float xg[4];
    {
        const v4f v = *(const v4f*)(xb + l0);
        xg[0] = v[0]; xg[1] = v[1]; xg[2] = v[2]; xg[3] = v[3];
    }

    float m[4] = {-INFINITY, -INFINITY, -INFINITY, -INFINITY};
    float a[3][4];
#pragma unroll
    for (int o = 0; o < 3; ++o) {
        const v4f p = *(const v4f*)(proj + o * L + l0);
        a[o][0] = p[0]; a[o][1] = p[1]; a[o][2] = p[2]; a[o][3] = p[3];
    }

#pragma unroll
    for (int c = 1; c < NCH; ++c) {
        const v4f v = *(const v4f*)(xb + c * L + l0);
        const float w0 = sW[0][c - 1];
        const float w1 = sW[1][c - 1];
        const float w2 = sW[2][c - 1];
#pragma unroll
        for (int j = 0; j < 4; ++j) {
            m[j] = fmaxf(m[j], v[j]);
            a[0][j] = fmaf(w0, v[j], a[0][j]);
            a[1][j] = fmaf(w1, v[j], a[1][j]);
            a[2][j] = fmaf(w2, v[j], a[2][j]);
        }
    }

    float wss[3][4];
#pragma unroll
    for (int o = 0; o < 3; ++o) {
        const v4f s = *(const v4f*)(ss_hmm + o * L + l0);
        wss[o][0] = s[0]; wss[o][1] = s[1]; wss[o][2] = s[2]; wss[o][3] = s[3];
    }

    float lsum = 0.0f, lcnt = 0.0f;
#pragma unroll
    for (int j = 0; j < 4; ++j) {
        if (m[j] > xg[j]) {  // argmax != 0 (first-occurrence tie -> gap)
            const float mm = fmaxf(a[0][j], fmaxf(a[1][j], a[2][j]));
            const float e0 = expf(a[0][j] - mm);
            const float e1 = expf(a[1][j] - mm);
            const float e2 = expf(a[2][j] - mm);
            const float inv = 1.0f / (e0 + e1 + e2);
            lsum = fmaf(wss[0][j] * e0 + wss[1][j] * e1 + wss[2][j] * e2, inv, lsum);
            lcnt += 1.0f;
        }
    }

    // 64-lane wave shuffle reduction
#pragma unroll
    for (int off = 32; off >= 1; off >>= 1) {
        lsum += __shfl_down(lsum, off);
        lcnt += __shfl_down(lcnt, off);
    }

    __shared__ float s_s[2], s_c[2];
    if ((t & 63) == 0) { s_s[t >> 6] = lsum; s_c[t >> 6] = lcnt; }
    __syncthreads();
    if (t == 0) {
        out[b] = logf((s_s[0] + s_s[1]) / (s_c[0] + s_c[1]));
    }
}

extern "C" void kernel_launch(void* const* d_in, const int* in_sizes, int n_in,
                              void* d_out, int out_size, void* d_ws, size_t ws_size,
                              hipStream_t stream) {
    const float* x       = (const float*)d_in[0];  // [4096,21,512]
    const float* seq_hmm = (const float*)d_in[1];  // [30,512]
    const float* ss_hmm  = (const float*)d_in[2];  // [3,512]
    const float* W       = (const float*)d_in[3];  // [3,50]
    const float* bvec    = (const float*)d_in[4];  // [3]
    float* out = (float*)d_out;                    // [4096]
    float* proj = (float*)d_ws;                    // 3*512 floats = 6 KB

    precompute_proj<<<1, L, 0, stream>>>(seq_hmm, W, bvec, proj);

    const int B = in_sizes[0] / (NCH * L);  // 4096
    qpml_main<<<B, 128, 0, stream>>>(x, ss_hmm, W, proj, out);
}